// Round 5
// baseline (958.027 us; speedup 1.0000x reference)
//
#include <hip/hip_runtime.h>

#define B_   1024
#define S_   128
#define H_   1024
#define V_   50000
#define EPSF 1e-10f

typedef float f32x4 __attribute__((ext_vector_type(4)));
typedef short s16x8 __attribute__((ext_vector_type(8)));  // 8 bf16 as raw bits
typedef short s16x4 __attribute__((ext_vector_type(4)));

// ws layout (pre-split path)
#define OFF_WHI 0ULL
#define OFF_WLO 102400000ULL
#define OFF_AHI 204800000ULL
#define OFF_ALO 206897152ULL
#define OFF_Z   208994304ULL
#define OFF_ST  208998400ULL
#define OFF_RT  209014784ULL
#define OFF_RV  209539072ULL
#define OFF_RL  210063360ULL
#define WS_NEED 210587648ULL

#define VMCNT(n) asm volatile("s_waitcnt vmcnt(" #n ")" ::: "memory")

// ---------- async global->LDS, 16B per lane (LDS ptr wave-uniform) ----------
__device__ __forceinline__ void gload_lds16(const void* g, void* l) {
  __builtin_amdgcn_global_load_lds(
      (const __attribute__((address_space(1))) void*)g,
      (__attribute__((address_space(3))) void*)l, 16, 0, 0);
}

// split fp32 -> bf16 hi (truncate) + bf16 lo (residual, truncate)
__device__ __forceinline__ void split8(f32x4 a, f32x4 b, s16x8& hi, s16x8& lo) {
  float x[8] = {a[0], a[1], a[2], a[3], b[0], b[1], b[2], b[3]};
#pragma unroll
  for (int j = 0; j < 8; ++j) {
    unsigned u = __float_as_uint(x[j]);
    hi[j] = (short)(u >> 16);
    float hf = __uint_as_float(u & 0xFFFF0000u);
    float l  = x[j] - hf;
    lo[j] = (short)(__float_as_uint(l) >> 16);
  }
}

// ================= pre-split: fp32 -> bf16 hi/lo planes =================
__global__ __launch_bounds__(256) void split_planes(
    const float* __restrict__ in, short* __restrict__ hi,
    short* __restrict__ lo, int n4) {
  for (int g = blockIdx.x * 256 + threadIdx.x; g < n4; g += gridDim.x * 256) {
    f32x4 x = ((const f32x4*)in)[g];
    s16x4 h, l;
#pragma unroll
    for (int j = 0; j < 4; ++j) {
      unsigned u = __float_as_uint(x[j]);
      h[j] = (short)(u >> 16);
      float hf = __uint_as_float(u & 0xFFFF0000u);
      l[j] = (short)(__float_as_uint(x[j] - hf) >> 16);
    }
    ((s16x4*)hi)[g] = h;
    ((s16x4*)lo)[g] = l;
  }
}

__global__ void zeroZ(float* Z) { Z[blockIdx.x * 256 + threadIdx.x] = 0.f; }

// ================= GEMM 256x256, 8 waves, 3-phase K-tiles, counted vmcnt ====
// planes: 0=Ahi 1=Alo 2=Bhi 3=Blo, each [256][32] bf16 = 16 KB, dbuf = 128 KB.
// Per K-tile(32): P1{issue U1(t+1)=Ahi,Bhi; read ahi,bhi; 32 MFMA hh; vmcnt(6)}
//                 P2{issue U2=Blo; read blo; 32 MFMA hl; vmcnt(6)}
//                 P3{issue U3=Alo; read alo; 32 MFMA lh; vmcnt(4)}
// Derived waits guarantee each phase's staged unit landed; loads stay in
// flight across barriers (never drain to 0 mid-loop).
constexpr int NBT = 196;  // ceil(50000/256)

__global__ __launch_bounds__(512, 2) void gemm8(
    const short* __restrict__ Whi, const short* __restrict__ Wlo,
    const short* __restrict__ Ahi, const short* __restrict__ Alo,
    const float* __restrict__ bias, float* __restrict__ out,
    float* __restrict__ Z) {
  __shared__ short lds[2][4][256 * 32];  // 128 KB

  int bid = blockIdx.x;
  int xcd = bid & 7;
  int t8  = bid >> 3;       // 0..99
  int mb  = t8 & 3;
  int nbg = t8 >> 2;        // 0..24
  int nb  = nbg * 8 + xcd;
  if (nb >= NBT) return;

  const int brow = mb * 256;
  const int bcol = nb * 256;
  const int tid  = threadIdx.x;
  const int lane = tid & 63;
  const int wid  = tid >> 6;   // 0..7
  const int wm   = wid >> 2;   // 0..1
  const int wn   = wid & 3;    // 0..3

  // staging: wave w lane l -> row = i*128 + w*16 + (l>>2), kc = (l&3)*8
  const int srow = wid * 16 + (lane >> 2);  // 0..127
  const int skc  = (lane & 3) * 8;
  const short* aHi0 = Ahi + (size_t)(brow + srow) * H_ + skc;
  const short* aHi1 = aHi0 + 128 * H_;
  const short* aLo0 = Alo + (size_t)(brow + srow) * H_ + skc;
  const short* aLo1 = aLo0 + 128 * H_;
  int v0 = bcol + srow;       if (v0 > V_ - 1) v0 = V_ - 1;
  int v1 = bcol + 128 + srow; if (v1 > V_ - 1) v1 = V_ - 1;
  const short* bHi0 = Whi + (size_t)v0 * H_ + skc;
  const short* bHi1 = Whi + (size_t)v1 * H_ + skc;
  const short* bLo0 = Wlo + (size_t)v0 * H_ + skc;
  const short* bLo1 = Wlo + (size_t)v1 * H_ + skc;
  const int sdst = wid * 512;  // shorts; HW adds lane*16B

  auto stageU1 = [&](int bufi, int k0) {  // Ahi + Bhi (4 loads/thread)
    gload_lds16(aHi0 + k0, &lds[bufi][0][0] + sdst);
    gload_lds16(aHi1 + k0, &lds[bufi][0][4096] + sdst);
    gload_lds16(bHi0 + k0, &lds[bufi][2][0] + sdst);
    gload_lds16(bHi1 + k0, &lds[bufi][2][4096] + sdst);
  };
  auto stageU2 = [&](int bufi, int k0) {  // Blo (2 loads/thread)
    gload_lds16(bLo0 + k0, &lds[bufi][3][0] + sdst);
    gload_lds16(bLo1 + k0, &lds[bufi][3][4096] + sdst);
  };
  auto stageU3 = [&](int bufi, int k0) {  // Alo (2 loads/thread)
    gload_lds16(aLo0 + k0, &lds[bufi][1][0] + sdst);
    gload_lds16(aLo1 + k0, &lds[bufi][1][4096] + sdst);
  };

  const int kg   = lane >> 4;      // 0..3 (k octet)
  const int r15  = lane & 15;
  const int aoff = (wm * 128 + r15) * 32 + kg * 8;  // + mi*512
  const int boff = (wn * 64 + r15) * 32 + kg * 8;   // + ni*512

  f32x4 acc[8][4];
#pragma unroll
  for (int i = 0; i < 8; ++i)
#pragma unroll
    for (int j = 0; j < 4; ++j) acc[i][j] = (f32x4){0.f, 0.f, 0.f, 0.f};

  // prologue: stage tile 0 (units in order), wait U1, barrier
  stageU1(0, 0);
  stageU2(0, 0);
  stageU3(0, 0);
  VMCNT(4);
  __builtin_amdgcn_s_barrier();

  int buf = 0;
#pragma unroll 1
  for (int t = 0; t < 32; ++t) {
    const int k0n  = (t + 1) * 32;
    const bool more = (t < 31);
    const short* P0 = &lds[buf][0][0];
    const short* P1p = &lds[buf][1][0];
    const short* P2p = &lds[buf][2][0];
    const short* P3p = &lds[buf][3][0];
    s16x8 a[8], bh[4], bl[4];

    // ---- phase 1: hh ----
    if (more) stageU1(buf ^ 1, k0n);
#pragma unroll
    for (int mi = 0; mi < 8; ++mi) a[mi] = *(const s16x8*)(P0 + aoff + mi * 512);
#pragma unroll
    for (int ni = 0; ni < 4; ++ni) bh[ni] = *(const s16x8*)(P2p + boff + ni * 512);
    __builtin_amdgcn_s_setprio(1);
#pragma unroll
    for (int mi = 0; mi < 8; ++mi)
#pragma unroll
      for (int ni = 0; ni < 4; ++ni)
        acc[mi][ni] = __builtin_amdgcn_mfma_f32_16x16x32_bf16(a[mi], bh[ni], acc[mi][ni], 0, 0, 0);
    __builtin_amdgcn_s_setprio(0);
    if (more) { VMCNT(6); } else { VMCNT(2); }
    __builtin_amdgcn_s_barrier();

    // ---- phase 2: hl (reuse ahi regs) ----
    if (more) stageU2(buf ^ 1, k0n);
#pragma unroll
    for (int ni = 0; ni < 4; ++ni) bl[ni] = *(const s16x8*)(P3p + boff + ni * 512);
    __builtin_amdgcn_s_setprio(1);
#pragma unroll
    for (int mi = 0; mi < 8; ++mi)
#pragma unroll
      for (int ni = 0; ni < 4; ++ni)
        acc[mi][ni] = __builtin_amdgcn_mfma_f32_16x16x32_bf16(a[mi], bl[ni], acc[mi][ni], 0, 0, 0);
    __builtin_amdgcn_s_setprio(0);
    if (more) { VMCNT(6); } else { VMCNT(0); }
    __builtin_amdgcn_s_barrier();

    // ---- phase 3: lh (reuse bhi regs) ----
    if (more) stageU3(buf ^ 1, k0n);
#pragma unroll
    for (int mi = 0; mi < 8; ++mi) a[mi] = *(const s16x8*)(P1p + aoff + mi * 512);
    __builtin_amdgcn_s_setprio(1);
#pragma unroll
    for (int mi = 0; mi < 8; ++mi)
#pragma unroll
      for (int ni = 0; ni < 4; ++ni)
        acc[mi][ni] = __builtin_amdgcn_mfma_f32_16x16x32_bf16(a[mi], bh[ni], acc[mi][ni], 0, 0, 0);
    __builtin_amdgcn_s_setprio(0);
    if (more) {
      VMCNT(4);
      __builtin_amdgcn_s_barrier();
    }
    buf ^= 1;
  }

  // epilogue: store logits (+bias) and per-row exp-sums into Z.
  const int colbase = bcol + wn * 64 + r15;
  const int rowbase = brow + wm * 128 + (kg << 2);
  float bv[4];
  bool  cv[4];
#pragma unroll
  for (int ni = 0; ni < 4; ++ni) {
    int col = colbase + ni * 16;
    cv[ni] = (col < V_);
    bv[ni] = bias[cv[ni] ? col : (V_ - 1)];
  }
#pragma unroll
  for (int ni = 0; ni < 4; ++ni) {
    if (cv[ni]) {
      int col = colbase + ni * 16;
#pragma unroll
      for (int mi = 0; mi < 8; ++mi) {
        int row0 = rowbase + mi * 16;
#pragma unroll
        for (int j = 0; j < 4; ++j)
          out[(size_t)(row0 + j) * V_ + col] = acc[mi][ni][j] + bv[ni];
      }
    }
  }
#pragma unroll
  for (int mi = 0; mi < 8; ++mi) {
#pragma unroll
    for (int j = 0; j < 4; ++j) {
      float s = 0.f;
#pragma unroll
      for (int ni = 0; ni < 4; ++ni)
        if (cv[ni]) s += __expf(acc[mi][ni][j] + bv[ni]);
      s += __shfl_xor(s, 1);
      s += __shfl_xor(s, 2);
      s += __shfl_xor(s, 4);
      s += __shfl_xor(s, 8);
      if (r15 == 0) atomicAdd(&Z[rowbase + mi * 16 + j], s);
    }
  }
}

// ================= stats per row =================
__global__ __launch_bounds__(128) void stats_k(
    const float* __restrict__ out, const float* __restrict__ attn,
    const int* __restrict__ src, const int* __restrict__ algn,
    const float* __restrict__ Z, f32x4* __restrict__ stats,
    int* __restrict__ rec_tgt, float* __restrict__ rec_val,
    float* __restrict__ rec_logit) {
  __shared__ float sVal[S_];
  __shared__ int   sTgt[S_];
  __shared__ float sRed[2];
  __shared__ float sScat0;

  const int b = blockIdx.x;
  const int tid = threadIdx.x;
  const int lane = tid & 63, wid = tid >> 6;
  const float* row = out + (size_t)b * V_;

  if (tid == 0) sScat0 = 0.f;
  const float l4 = row[4];
  const float cp = 1.f / (1.f + __expf(-l4));
  {
    int sv = src[b * S_ + tid];
    sTgt[tid] = algn[sv];
    sVal[tid] = attn[b * S_ + tid] * cp;
  }
  __syncthreads();
  int tgt = sTgt[tid];
  bool first = true;
  float total = 0.f;
  for (int s2 = 0; s2 < S_; ++s2) {
    bool eq = (sTgt[s2] == tgt);
    if (eq && s2 < tid) first = false;
    if (eq) total += sVal[s2];
  }
  int o = b * S_ + tid;
  if (first && tgt != 0) {
    rec_tgt[o]   = tgt;
    rec_val[o]   = total;
    rec_logit[o] = row[tgt];
  } else {
    rec_tgt[o] = -1;
  }
  if (first && tgt == 0) sScat0 = total;

  float sumv = sVal[tid];
#pragma unroll
  for (int off = 32; off; off >>= 1) sumv += __shfl_down(sumv, off);
  if (lane == 0) sRed[wid] = sumv;
  __syncthreads();
  if (tid == 0) {
    float sumval = sRed[0] + sRed[1];
    float Zmod   = Z[b] - __expf(l4) + __expf(EPSF);
    float p0     = __expf(row[0]) / Zmod;
    float omc    = 1.f - cp;
    float norm   = omc + sumval + EPSF - p0 * omc - sScat0;
    f32x4 st;
    st[0] = omc / (Zmod * norm);
    st[1] = __logf(EPSF / norm + EPSF);
    st[2] = 1.f / norm;
    st[3] = 0.f;
    stats[b] = st;
  }
}

// ================= final elementwise transform (2D grid, no div/mod) ========
__global__ __launch_bounds__(256) void transform2(
    float* __restrict__ out, const f32x4* __restrict__ stats) {
  const int b = blockIdx.y;
  f32x4 st = stats[b];
  float* row = out + (size_t)b * V_;
  int cg0 = blockIdx.x * 512 + threadIdx.x;
#pragma unroll
  for (int rep = 0; rep < 2; ++rep) {
    int cg = cg0 + rep * 256;
    if (cg < V_ / 4) {
      f32x4 f = ((const f32x4*)row)[cg];
      int vb  = cg * 4;
      f32x4 r;
#pragma unroll
      for (int j = 0; j < 4; ++j) {
        float x = f[j];
        int v   = vb + j;
        if (v == 4) x = EPSF;
        float y = __logf(__expf(x) * st[0] + EPSF);
        if (v == 0) y = st[1];
        r[j] = y;
      }
      ((f32x4*)row)[cg] = r;
    }
  }
}

// ================= scatter fixup =================
__global__ __launch_bounds__(128) void fixup_k(
    float* __restrict__ out, const f32x4* __restrict__ stats,
    const int* __restrict__ rec_tgt, const float* __restrict__ rec_val,
    const float* __restrict__ rec_logit) {
  int b = blockIdx.x, s = threadIdx.x;
  int o = b * S_ + s;
  int t = rec_tgt[o];
  if (t < 0) return;
  f32x4 st = stats[b];
  float x  = (t == 4) ? EPSF : rec_logit[o];
  out[(size_t)b * V_ + t] = __logf(__expf(x) * st[0] + st[2] * rec_val[o] + EPSF);
}

// ======================================================================
// =============== FALLBACK path (ws too small) =========================
// ======================================================================
__global__ __launch_bounds__(256, 2) void gemm_fb(
    const float* __restrict__ hid, const float* __restrict__ W,
    const float* __restrict__ bias, float* __restrict__ out) {
  __shared__ float ldsA[2][128 * 32];
  __shared__ float ldsB[2][128 * 32];
  int bid = blockIdx.x;
  int xcd = bid & 7;
  int t8  = bid >> 3;
  int mb  = t8 & 7;
  int nbg = t8 >> 3;
  int nb  = nbg * 8 + xcd;
  if (nb >= 391) return;
  const int brow = mb * 128;
  const int bcol = nb * 128;
  const int tid  = threadIdx.x;
  const int lane = tid & 63;
  const int wid  = tid >> 6;
  const int wr   = wid >> 1;
  const int wc   = wid & 1;
  const float* gA[4];
  const float* gB[4];
#pragma unroll
  for (int i = 0; i < 4; ++i) {
    int row = i * 32 + (tid >> 3);
    int g   = (tid & 7) ^ (row & 7);
    gA[i] = hid + (size_t)(brow + row) * H_ + g * 4;
    int gv = bcol + row;
    if (gv > V_ - 1) gv = V_ - 1;
    gB[i] = W + (size_t)gv * H_ + g * 4;
  }
  auto stage = [&](int bufi, int k0) {
#pragma unroll
    for (int i = 0; i < 4; ++i)
      gload_lds16(gA[i] + k0, (char*)(&ldsA[bufi][0]) + i * 4096 + wid * 1024);
#pragma unroll
    for (int i = 0; i < 4; ++i)
      gload_lds16(gB[i] + k0, (char*)(&ldsB[bufi][0]) + i * 4096 + wid * 1024);
  };
  const int kg  = lane >> 4;
  const int r15 = lane & 15;
  int offA0[4], offA1[4], offB0[4], offB1[4];
#pragma unroll
  for (int i = 0; i < 4; ++i) {
    int ra = wr * 64 + i * 16 + r15;
    int wa = ra & 7;
    offA0[i] = ra * 128 + ((((kg << 1) | 0) ^ wa) << 4);
    offA1[i] = ra * 128 + ((((kg << 1) | 1) ^ wa) << 4);
    int rb = wc * 64 + i * 16 + r15;
    int wb = rb & 7;
    offB0[i] = rb * 128 + ((((kg << 1) | 0) ^ wb) << 4);
    offB1[i] = rb * 128 + ((((kg << 1) | 1) ^ wb) << 4);
  }
  f32x4 acc[4][4];
#pragma unroll
  for (int i = 0; i < 4; ++i)
#pragma unroll
    for (int j = 0; j < 4; ++j) acc[i][j] = (f32x4){0.f, 0.f, 0.f, 0.f};
  stage(0, 0);
  __syncthreads();
  int buf = 0;
#pragma unroll 1
  for (int t = 0; t < 32; ++t) {
    if (t < 31) stage(buf ^ 1, (t + 1) * 32);
    const char* bA = (const char*)(&ldsA[buf][0]);
    const char* bB = (const char*)(&ldsB[buf][0]);
    s16x8 ah[4], al[4], bh[4], bl[4];
#pragma unroll
    for (int mi = 0; mi < 4; ++mi)
      split8(*(const f32x4*)(bA + offA0[mi]), *(const f32x4*)(bA + offA1[mi]),
             ah[mi], al[mi]);
#pragma unroll
    for (int ni = 0; ni < 4; ++ni)
      split8(*(const f32x4*)(bB + offB0[ni]), *(const f32x4*)(bB + offB1[ni]),
             bh[ni], bl[ni]);
#pragma unroll
    for (int mi = 0; mi < 4; ++mi)
#pragma unroll
      for (int ni = 0; ni < 4; ++ni) {
        acc[mi][ni] = __builtin_amdgcn_mfma_f32_16x16x32_bf16(ah[mi], bh[ni], acc[mi][ni], 0, 0, 0);
        acc[mi][ni] = __builtin_amdgcn_mfma_f32_16x16x32_bf16(ah[mi], bl[ni], acc[mi][ni], 0, 0, 0);
        acc[mi][ni] = __builtin_amdgcn_mfma_f32_16x16x32_bf16(al[mi], bh[ni], acc[mi][ni], 0, 0, 0);
      }
    __syncthreads();
    buf ^= 1;
  }
  const int colbase = bcol + wc * 64 + r15;
  const int rowbase = brow + wr * 64 + ((lane >> 4) << 2);
#pragma unroll
  for (int ni = 0; ni < 4; ++ni) {
    int col = colbase + ni * 16;
    if (col < V_) {
      float bv = bias[col];
#pragma unroll
      for (int mi = 0; mi < 4; ++mi) {
        int row0 = rowbase + mi * 16;
#pragma unroll
        for (int j = 0; j < 4; ++j)
          out[(size_t)(row0 + j) * V_ + col] = acc[mi][ni][j] + bv;
      }
    }
  }
}

__global__ __launch_bounds__(256) void row_finish(
    float* __restrict__ out, const float* __restrict__ attn,
    const int* __restrict__ src, const int* __restrict__ algn) {
  __shared__ float sRed[4];
  __shared__ float sBro[4];
  __shared__ float sSt[4];
  __shared__ float sVal[S_];
  __shared__ int   sTgt[S_];
  __shared__ int   rTgt[S_];
  __shared__ float rVal[S_];
  __shared__ float rLog[S_];
  const int b = blockIdx.x;
  const int tid = threadIdx.x;
  const int lane = tid & 63, wid = tid >> 6;
  float* row = out + (size_t)b * V_;
  float z = 0.f;
  for (int c = tid; c < V_ / 4; c += 256) {
    f32x4 f = ((const f32x4*)row)[c];
    z += __expf(f[0]) + __expf(f[1]) + __expf(f[2]) + __expf(f[3]);
  }
#pragma unroll
  for (int off = 32; off; off >>= 1) z += __shfl_down(z, off);
  if (lane == 0) sRed[wid] = z;
  if (tid == 0) sBro[2] = 0.f;
  __syncthreads();
  if (tid == 0) {
    float Zr = sRed[0] + sRed[1] + sRed[2] + sRed[3];
    float l4 = row[4];
    sBro[0] = Zr - __expf(l4) + __expf(EPSF);
    sBro[1] = 1.f / (1.f + __expf(-l4));
  }
  __syncthreads();
  const float Z = sBro[0], cp = sBro[1];
  if (tid < S_) {
    int sv = src[b * S_ + tid];
    sTgt[tid] = algn[sv];
    sVal[tid] = attn[b * S_ + tid] * cp;
  }
  __syncthreads();
  float sumv = 0.f;
  if (tid < S_) {
    int tgt = sTgt[tid];
    bool first = true;
    float total = 0.f;
    for (int s2 = 0; s2 < S_; ++s2) {
      bool eq = (sTgt[s2] == tgt);
      if (eq && s2 < tid) first = false;
      if (eq) total += sVal[s2];
    }
    if (first && tgt != 0) {
      rTgt[tid] = tgt;
      rVal[tid] = total;
      rLog[tid] = row[tgt];
    } else {
      rTgt[tid] = -1;
    }
    if (first && tgt == 0) sBro[2] = total;
    sumv = sVal[tid];
  }
#pragma unroll
  for (int off = 32; off; off >>= 1) sumv += __shfl_down(sumv, off);
  if (lane == 0) sRed[wid] = sumv;
  __syncthreads();
  if (tid == 0) {
    float sumval = sRed[0] + sRed[1] + sRed[2] + sRed[3];
    float scat0  = sBro[2];
    float p0     = __expf(row[0]) / Z;
    float omc    = 1.f - cp;
    float norm   = omc + sumval + EPSF - p0 * omc - scat0;
    sSt[0] = omc / (Z * norm);
    sSt[1] = __logf(EPSF / norm + EPSF);
    sSt[2] = 1.f / norm;
  }
  __syncthreads();
  const float st0 = sSt[0], st1 = sSt[1], invn = sSt[2];
  for (int c = tid; c < V_ / 4; c += 256) {
    f32x4 f = ((const f32x4*)row)[c];
    int vb  = c * 4;
    f32x4 r;
#pragma unroll
    for (int j = 0; j < 4; ++j) {
      float x = f[j];
      int v   = vb + j;
      if (v == 4) x = EPSF;
      float y = __logf(__expf(x) * st0 + EPSF);
      if (v == 0) y = st1;
      r[j] = y;
    }
    ((f32x4*)row)[c] = r;
  }
  __syncthreads();
  if (tid < S_) {
    int t = rTgt[tid];
    if (t >= 0) {
      float x = (t == 4) ? EPSF : rLog[tid];
      row[t] = __logf(__expf(x) * st0 + invn * rVal[tid] + EPSF);
    }
  }
}

extern "C" void kernel_launch(void* const* d_in, const int* in_sizes, int n_in,
                              void* d_out, int out_size, void* d_ws,
                              size_t ws_size, hipStream_t stream) {
  const float* hid  = (const float*)d_in[0];
  const int*   src  = (const int*)d_in[1];
  const float* attn = (const float*)d_in[2];
  const float* W    = (const float*)d_in[3];
  const float* bias = (const float*)d_in[4];
  const int*   algn = (const int*)d_in[5];
  float* out = (float*)d_out;
  (void)in_sizes; (void)n_in; (void)out_size;

  if (ws_size >= WS_NEED) {
    char* ws = (char*)d_ws;
    short* Whi = (short*)(ws + OFF_WHI);
    short* Wlo = (short*)(ws + OFF_WLO);
    short* Ahi = (short*)(ws + OFF_AHI);
    short* Alo = (short*)(ws + OFF_ALO);
    float* Z   = (float*)(ws + OFF_Z);
    f32x4* st  = (f32x4*)(ws + OFF_ST);
    int*   rt  = (int*)(ws + OFF_RT);
    float* rv  = (float*)(ws + OFF_RV);
    float* rl  = (float*)(ws + OFF_RL);

    split_planes<<<dim3(2048), dim3(256), 0, stream>>>(W, Whi, Wlo, V_ * H_ / 4);
    split_planes<<<dim3(256), dim3(256), 0, stream>>>(hid, Ahi, Alo, B_ * H_ / 4);
    zeroZ<<<dim3(4), dim3(256), 0, stream>>>(Z);
    gemm8<<<dim3(800), dim3(512), 0, stream>>>(Whi, Wlo, Ahi, Alo, bias, out, Z);
    stats_k<<<dim3(B_), dim3(S_), 0, stream>>>(out, attn, src, algn, Z, st, rt, rv, rl);
    transform2<<<dim3(25, B_), dim3(256), 0, stream>>>(out, st);
    fixup_k<<<dim3(B_), dim3(S_), 0, stream>>>(out, st, rt, rv, rl);
  } else {
    gemm_fb<<<dim3(3136), dim3(256), 0, stream>>>(hid, W, bias, out);
    row_finish<<<dim3(B_), dim3(256), 0, stream>>>(out, attn, src, algn);
  }
}